// Round 6
// baseline (369.186 us; speedup 1.0000x reference)
//
#include <hip/hip_runtime.h>
#include <math.h>

#define NN 16384
#define BB 128
#define FF 32
#define RR 20
#define EE 262144
#define NCH 4
#define CHE (EE / NCH)

__device__ __forceinline__ float sspf(float x) {
  // softplus(x) - log(2), numerically stable
  return fmaxf(x, 0.0f) + log1pf(expf(-fabsf(x))) - 0.69314718055994531f;
}

// ---------------- K1: node embeddings hsv[n*32+f] = {hs, hvx, hvy, hvz} ----------------
__global__ __launch_bounds__(256) void k_embed(const float* __restrict__ x,
        const float* __restrict__ ws, const float* __restrict__ wv,
        float4* __restrict__ hsv) {
  int tid = blockIdx.x * 256 + threadIdx.x;   // N*8 threads
  int n = tid >> 3, fq = tid & 7;
  const float* xr = x + (size_t)n * 512;
  float acc[4][4];
#pragma unroll
  for (int k = 0; k < 4; k++)
#pragma unroll
    for (int c = 0; c < 4; c++) acc[k][c] = 0.f;
  for (int bq = 0; bq < 32; bq++) {
    float4 xs4 = *(const float4*)(xr + 4 * bq);
    float4 a0 = *(const float4*)(xr + 128 + 12 * bq);
    float4 a1 = *(const float4*)(xr + 128 + 12 * bq + 4);
    float4 a2 = *(const float4*)(xr + 128 + 12 * bq + 8);
    float xsv[4] = {xs4.x, xs4.y, xs4.z, xs4.w};
    float vv[4][3];
    vv[0][0] = a0.x; vv[0][1] = a0.y; vv[0][2] = a0.z;
    vv[1][0] = a0.w; vv[1][1] = a1.x; vv[1][2] = a1.y;
    vv[2][0] = a1.z; vv[2][1] = a1.w; vv[2][2] = a2.x;
    vv[3][0] = a2.y; vv[3][1] = a2.z; vv[3][2] = a2.w;
#pragma unroll
    for (int bb = 0; bb < 4; bb++) {
      int b = 4 * bq + bb;
      float4 w_s = *(const float4*)(ws + b * 32 + 4 * fq);
      float4 w_v = *(const float4*)(wv + b * 32 + 4 * fq);
      float wsx[4] = {w_s.x, w_s.y, w_s.z, w_s.w};
      float wvx[4] = {w_v.x, w_v.y, w_v.z, w_v.w};
#pragma unroll
      for (int k = 0; k < 4; k++) {
        acc[k][0] += xsv[bb] * wsx[k];
        acc[k][1] += vv[bb][0] * wvx[k];
        acc[k][2] += vv[bb][1] * wvx[k];
        acc[k][3] += vv[bb][2] * wvx[k];
      }
    }
  }
  const float sc = 0.088388347648318447f;  // 1/sqrt(128)
#pragma unroll
  for (int k = 0; k < 4; k++) {
    float4 o;
    o.x = acc[k][0] * sc; o.y = acc[k][1] * sc;
    o.z = acc[k][2] * sc; o.w = acc[k][3] * sc;
    hsv[(size_t)n * 32 + 4 * fq + k] = o;
  }
}

// ---------------- CSR build ----------------
__global__ __launch_bounds__(256) void k_count(const int* __restrict__ idx_i,
        int* __restrict__ cnt, int* __restrict__ pos) {
  int e = blockIdx.x * 256 + threadIdx.x;
  pos[e] = atomicAdd(cnt + idx_i[e], 1);
}

__global__ __launch_bounds__(256) void k_scan(const int* __restrict__ cnt,
        int* __restrict__ offs) {
  __shared__ int part[256];
  int t = threadIdx.x;
  int s = 0;
  for (int i = t * 64; i < t * 64 + 64; ++i) s += cnt[i];
  part[t] = s;
  __syncthreads();
  if (t == 0) {
    int run = 0;
    for (int i = 0; i < 256; i++) { int v = part[i]; part[i] = run; run += v; }
    offs[NN] = run;
  }
  __syncthreads();
  int run = part[t];
  for (int i = t * 64; i < t * 64 + 64; ++i) { offs[i] = run; run += cnt[i]; }
}

// also permutes idx_j and Yr into CSR order so k_agg streams them sequentially
__global__ __launch_bounds__(256) void k_fill(const int* __restrict__ idx_i,
        const int* __restrict__ idx_j, const float* __restrict__ Yr,
        const int* __restrict__ pos, const int* __restrict__ offs,
        int* __restrict__ elist, int* __restrict__ idxj_csr,
        float4* __restrict__ Yr_csr) {
  int e = blockIdx.x * 256 + threadIdx.x;
  int slot = offs[idx_i[e]] + pos[e];
  elist[slot] = e;
  idxj_csr[slot] = idx_j[e];
  Yr_csr[slot] = *(const float4*)(Yr + (size_t)e * 4);
}

// ---------------- fused vector output weight: Wv = w1v @ w2v * 1/sqrt(64*128) ----------------
__global__ __launch_bounds__(256) void k_wv(const float* __restrict__ w1v,
        const float* __restrict__ w2v, float* __restrict__ Wv) {
  int o = blockIdx.x * 256 + threadIdx.x;   // 8192
  int m = o >> 7, d = o & 127;
  float s = 0.f;
  for (int b = 0; b < 128; b++) s += w1v[m * 128 + b] * w2v[b * 128 + d];
  Wv[o] = s * 0.011048543456039804f;
}

// ---------------- k_wab: CSR-slot-major fused filter MLP ----------------
// Per 64-slot tile: gather fij rows, h = ssp(fij@W1+b1) in LDS, dense fp32
// GEMM h @ W2c (128 used cols) + b2, *rcut, coalesced CSR-order write.
__global__ __launch_bounds__(256) void k_wab(
        const float* __restrict__ fij, const float* __restrict__ rcut,
        const int* __restrict__ elist,
        const float* __restrict__ W1, const float* __restrict__ b1,
        const float* __restrict__ W2, const float* __restrict__ b2,
        float* __restrict__ Wab, int c0) {
  __shared__ int selist[64];
  __shared__ float sW1[640];
  __shared__ float sb1[32];
  __shared__ float sW2c[4096];     // [p][128] compact used cols (4f+k <- 6f+k)
  __shared__ float sb2c[128];
  __shared__ float sfij[20 * 66];  // [r][el], pad 66
  __shared__ float sh[64 * 36];    // [el][fp], pad 36 (16B-aligned rows)
  __shared__ float srct[64];
  int t = threadIdx.x;
  int s0 = c0 + blockIdx.x * 64;
  if (t < 64) selist[t] = elist[s0 + t];
  for (int i = t; i < 640; i += 256) sW1[i] = W1[i];
  if (t < 32) sb1[t] = b1[t];
  for (int i = t; i < 4096; i += 256) {
    int p = i >> 7, c = i & 127;
    sW2c[i] = W2[p * 192 + 6 * (c >> 2) + (c & 3)];
  }
  if (t < 128) sb2c[t] = b2[6 * (t >> 2) + (t & 3)];
  __syncthreads();
  for (int i = t; i < 1280; i += 256) {
    int row = i / 20, col = i - row * 20;
    sfij[col * 66 + row] = fij[(size_t)selist[row] * 20 + col];
  }
  if (t < 64) srct[t] = rcut[selist[t]];
  __syncthreads();
  {
    int el = t & 63, fp0 = (t >> 6) * 8;
    float acc[8];
#pragma unroll
    for (int i = 0; i < 8; i++) acc[i] = sb1[fp0 + i];
#pragma unroll
    for (int r = 0; r < 20; r++) {
      float fe = sfij[r * 66 + el];
      float4 wA = *(const float4*)(sW1 + r * 32 + fp0);
      float4 wB = *(const float4*)(sW1 + r * 32 + fp0 + 4);
      acc[0] += fe * wA.x; acc[1] += fe * wA.y;
      acc[2] += fe * wA.z; acc[3] += fe * wA.w;
      acc[4] += fe * wB.x; acc[5] += fe * wB.y;
      acc[6] += fe * wB.z; acc[7] += fe * wB.w;
    }
#pragma unroll
    for (int i = 0; i < 8; i++) sh[el * 36 + fp0 + i] = sspf(acc[i]);
  }
  __syncthreads();
  {
    int eq = t >> 4, cq = (t & 15) * 8;   // 4 edges x 8 cols per thread
    float acc[4][8];
#pragma unroll
    for (int j = 0; j < 4; j++)
#pragma unroll
      for (int i = 0; i < 8; i++) acc[j][i] = sb2c[cq + i];
#pragma unroll
    for (int p = 0; p < 32; p++) {
      float4 wA = *(const float4*)(sW2c + p * 128 + cq);
      float4 wB = *(const float4*)(sW2c + p * 128 + cq + 4);
      float w[8] = {wA.x, wA.y, wA.z, wA.w, wB.x, wB.y, wB.z, wB.w};
#pragma unroll
      for (int j = 0; j < 4; j++) {
        float hh = sh[(4 * eq + j) * 36 + p];
#pragma unroll
        for (int i = 0; i < 8; i++) acc[j][i] += hh * w[i];
      }
    }
#pragma unroll
    for (int j = 0; j < 4; j++) {
      float rc = srct[4 * eq + j];
      float* base = Wab + (size_t)(blockIdx.x * 64 + 4 * eq + j) * 128 + cq;
      float4 o1, o2;
      o1.x = acc[j][0] * rc; o1.y = acc[j][1] * rc;
      o1.z = acc[j][2] * rc; o1.w = acc[j][3] * rc;
      o2.x = acc[j][4] * rc; o2.y = acc[j][5] * rc;
      o2.z = acc[j][6] * rc; o2.w = acc[j][7] * rc;
      *(float4*)base = o1;
      *(float4*)(base + 4) = o2;
    }
  }
}

// ---------------- k_agg: one wave per node; sequential CSR streams ----------------
// lane l: f = l&31, kh = l>>5 -> cols {4f+2kh, 4f+2kh+1}. Only random access is
// hsv[j], prefetched DEPTH-2 (j fetched 3 ahead, sv issued 2 ahead).
__global__ __launch_bounds__(256) void k_agg(
        const float2* __restrict__ Wab2, const float4* __restrict__ Yr_csr,
        const int* __restrict__ idxj_csr, const float4* __restrict__ hsv,
        const int* __restrict__ offs, float* __restrict__ nagg,
        int c0, int c1) {
  int t = threadIdx.x;
  int n = blockIdx.x * 4 + (t >> 6);
  int l = t & 63, f = l & 31, kh = l >> 5;
  int start = offs[n], end = offs[n + 1];
  int s = start > c0 ? start : c0;
  int eend = end < c1 ? end : c1;
  if (s >= eend) return;    // wave-uniform exit
  float a0 = 0, a1 = 0, a2 = 0, a3 = 0, a4 = 0, a5 = 0;
  int w2i = 2 * f + kh;
  int last = eend - 1;
  // prologue: iters s (cur) and s+1 staged; j for s+2 resident
  int i1 = s + 1 < last ? s + 1 : last;
  int i2 = s + 2 < last ? s + 2 : last;
  int j0 = idxj_csr[s];
  int j1 = idxj_csr[i1];
  int j2 = idxj_csr[i2];
  float4 y0 = Yr_csr[s];
  float4 y1 = Yr_csr[i1];
  float2 d0 = Wab2[(size_t)(s - c0) * 64 + w2i];
  float2 d1 = Wab2[(size_t)(i1 - c0) * 64 + w2i];
  float4 sv0 = hsv[(size_t)j0 * 32 + f];
  float4 sv1 = hsv[(size_t)j1 * 32 + f];
  for (int ei = s; ei < eend; ++ei) {
    int in2 = ei + 2 < last ? ei + 2 : last;
    int in3 = ei + 3 < last ? ei + 3 : last;
    float4 sv2 = hsv[(size_t)j2 * 32 + f];       // issue depth-2 load
    float4 y2 = Yr_csr[in2];
    float2 d2 = Wab2[(size_t)(in2 - c0) * 64 + w2i];
    int j3 = idxj_csr[in3];
    float ys = y0.x, yx = y0.y, yy = y0.z, yz = y0.w;
    float ss = sv0.x, vx = sv0.y, vy = sv0.z, vz = sv0.w;
    if (kh == 0) {
      a0 += ss * ys * d0.x;
      a1 += (vx * yx + vy * yy + vz * yz) * 0.57735026918962576f * d0.y;
    } else {
      a0 += ss * yx * d0.x; a1 += ss * yy * d0.x; a2 += ss * yz * d0.x;
      a3 += vx * ys * d0.y; a4 += vy * ys * d0.y; a5 += vz * ys * d0.y;
    }
    y0 = y1; y1 = y2; d0 = d1; d1 = d2; sv0 = sv1; sv1 = sv2; j2 = j3;
  }
  float* na = nagg + (size_t)n * 256;
  if (kh == 0) {
    na[f] += a0;
    na[32 + f] += a1;
  } else {
    na[64 + 3 * f + 0] += a0;  na[64 + 3 * f + 1] += a1;  na[64 + 3 * f + 2] += a2;
    na[160 + 3 * f + 0] += a3; na[160 + 3 * f + 1] += a4; na[160 + 3 * f + 2] += a5;
  }
}

// ---------------- output transforms: weights in LDS, 4-node batch per thread ----------------
__global__ __launch_bounds__(256) void k_os1(const float* __restrict__ na,
        const float* __restrict__ w1s, float* __restrict__ os1) {
  __shared__ float sw[8192];       // w1s 64x128, [m][d]
  int t = threadIdx.x;
  for (int i = t; i < 8192; i += 256) sw[i] = w1s[i];
  __syncthreads();
  int d = t & 127, g = t >> 7;
  int nb = blockIdx.x * 8 + g * 4;          // 2048 blocks, 8 nodes/block
  const float* rb = na + (size_t)nb * 256;
  float a[4] = {0, 0, 0, 0};
#pragma unroll
  for (int mq = 0; mq < 16; mq++) {
    float w0 = sw[(4 * mq + 0) * 128 + d];
    float w1 = sw[(4 * mq + 1) * 128 + d];
    float w2 = sw[(4 * mq + 2) * 128 + d];
    float w3 = sw[(4 * mq + 3) * 128 + d];
#pragma unroll
    for (int u = 0; u < 4; u++) {
      float4 x4 = *(const float4*)(rb + u * 256 + 4 * mq);
      a[u] += x4.x * w0 + x4.y * w1 + x4.z * w2 + x4.w * w3;
    }
  }
#pragma unroll
  for (int u = 0; u < 4; u++)
    os1[(size_t)(nb + u) * 128 + d] = sspf(a[u] * 0.125f);   // 1/sqrt(64)
}

__global__ __launch_bounds__(256) void k_os2(const float* __restrict__ os1,
        const float* __restrict__ w2s, float* __restrict__ out) {
  __shared__ float sw[16384];      // w2s 128x128 = 64 KB
  int t = threadIdx.x;
  for (int i = t; i < 16384; i += 256) sw[i] = w2s[i];
  __syncthreads();
  int d = t & 127, g = t >> 7;
  int nb = blockIdx.x * 8 + g * 4;          // 2048 blocks
  const float* rb = os1 + (size_t)nb * 128;
  float a[4] = {0, 0, 0, 0};
#pragma unroll
  for (int mq = 0; mq < 32; mq++) {
    float w0 = sw[(4 * mq + 0) * 128 + d];
    float w1 = sw[(4 * mq + 1) * 128 + d];
    float w2 = sw[(4 * mq + 2) * 128 + d];
    float w3 = sw[(4 * mq + 3) * 128 + d];
#pragma unroll
    for (int u = 0; u < 4; u++) {
      float4 x4 = *(const float4*)(rb + u * 128 + 4 * mq);
      a[u] += x4.x * w0 + x4.y * w1 + x4.z * w2 + x4.w * w3;
    }
  }
  const float sc = 0.088388347648318447f;   // 1/sqrt(128)
#pragma unroll
  for (int u = 0; u < 4; u++)
    out[(size_t)(nb + u) * 512 + d] = a[u] * sc;
}

__global__ __launch_bounds__(256) void k_ov(const float* __restrict__ na,
        const float* __restrict__ Wv, float* __restrict__ out) {
  __shared__ float sw[8192];       // Wv 64x128
  int t = threadIdx.x;
  for (int i = t; i < 8192; i += 256) sw[i] = Wv[i];
  __syncthreads();
  int d = t & 127, g = t >> 7;
  int nb = blockIdx.x * 8 + g * 4;          // 2048 blocks, 8 nodes/block
  const float* rb = na + (size_t)nb * 256 + 64;   // v_in rows: 192 floats
  float a[4][3];
#pragma unroll
  for (int u = 0; u < 4; u++) { a[u][0] = 0.f; a[u][1] = 0.f; a[u][2] = 0.f; }
#pragma unroll
  for (int mq = 0; mq < 16; mq++) {
    float w0 = sw[(4 * mq + 0) * 128 + d];
    float w1 = sw[(4 * mq + 1) * 128 + d];
    float w2 = sw[(4 * mq + 2) * 128 + d];
    float w3 = sw[(4 * mq + 3) * 128 + d];
#pragma unroll
    for (int u = 0; u < 4; u++) {
      const float* r = rb + u * 256 + 12 * mq;
      float4 p0 = *(const float4*)(r);
      float4 p1 = *(const float4*)(r + 4);
      float4 p2 = *(const float4*)(r + 8);
      a[u][0] += p0.x * w0 + p0.w * w1 + p1.z * w2 + p2.y * w3;
      a[u][1] += p0.y * w0 + p1.x * w1 + p1.w * w2 + p2.z * w3;
      a[u][2] += p0.z * w0 + p1.y * w1 + p2.x * w2 + p2.w * w3;
    }
  }
#pragma unroll
  for (int u = 0; u < 4; u++) {
    float* op = out + (size_t)(nb + u) * 512 + 128 + 3 * d;
    op[0] = a[u][0]; op[1] = a[u][1]; op[2] = a[u][2];
  }
}

extern "C" void kernel_launch(void* const* d_in, const int* in_sizes, int n_in,
                              void* d_out, int out_size, void* d_ws, size_t ws_size,
                              hipStream_t stream) {
  const float* x    = (const float*)d_in[0];
  const int*   idx_i = (const int*)d_in[1];
  const int*   idx_j = (const int*)d_in[2];
  const float* fij  = (const float*)d_in[3];
  const float* rcut = (const float*)d_in[4];
  const float* Yr   = (const float*)d_in[5];
  const float* w_s  = (const float*)d_in[6];
  const float* w_v  = (const float*)d_in[7];
  const float* W1   = (const float*)d_in[8];
  const float* b1   = (const float*)d_in[9];
  const float* W2   = (const float*)d_in[10];
  const float* b2   = (const float*)d_in[11];
  const float* w1s  = (const float*)d_in[12];
  const float* w1v  = (const float*)d_in[13];
  const float* w2s  = (const float*)d_in[14];
  const float* w2v  = (const float*)d_in[15];
  float* out = (float*)d_out;

  char* ws = (char*)d_ws;
  size_t off = 0;
  auto alloc = [&](size_t bytes) {
    void* p = ws + off;
    off += (bytes + 255) & ~(size_t)255;
    return p;
  };
  float4* hsv   = (float4*)alloc((size_t)NN * 32 * 16);
  float*  nagg  = (float*)alloc((size_t)NN * 256 * 4);
  float*  Wab   = (float*)alloc((size_t)CHE * 128 * 4);   // per-chunk; reused
  float*  os1   = Wab;    // alias: Wab dead before k_os1 runs
  float4* Yr_csr = (float4*)alloc((size_t)EE * 16);
  int* idxj_csr = (int*)alloc((size_t)EE * 4);
  float* Wv     = (float*)alloc((size_t)8192 * 4);
  int* cnt      = (int*)alloc((size_t)NN * 4);
  int* offs     = (int*)alloc((size_t)(NN + 1) * 4);
  int* pos      = (int*)alloc((size_t)EE * 4);
  int* elist    = (int*)alloc((size_t)EE * 4);

  hipMemsetAsync(cnt, 0, (size_t)NN * 4, stream);
  hipMemsetAsync(nagg, 0, (size_t)NN * 256 * 4, stream);
  k_count<<<EE / 256, 256, 0, stream>>>(idx_i, cnt, pos);
  k_scan<<<1, 256, 0, stream>>>(cnt, offs);
  k_fill<<<EE / 256, 256, 0, stream>>>(idx_i, idx_j, Yr, pos, offs,
                                       elist, idxj_csr, Yr_csr);
  k_embed<<<NN * 8 / 256, 256, 0, stream>>>(x, w_s, w_v, hsv);
  k_wv<<<32, 256, 0, stream>>>(w1v, w2v, Wv);
  for (int ch = 0; ch < NCH; ch++) {
    int c0 = ch * CHE, c1 = c0 + CHE;
    k_wab<<<CHE / 64, 256, 0, stream>>>(fij, rcut, elist, W1, b1, W2, b2,
                                        Wab, c0);
    k_agg<<<NN / 4, 256, 0, stream>>>((const float2*)Wab, Yr_csr, idxj_csr,
                                      hsv, offs, nagg, c0, c1);
  }
  k_os1<<<NN / 8, 256, 0, stream>>>(nagg, w1s, os1);
  k_os2<<<NN / 8, 256, 0, stream>>>(os1, w2s, out);
  k_ov<<<NN / 8, 256, 0, stream>>>(nagg, Wv, out);
}

// Round 7
// 309.093 us; speedup vs baseline: 1.1944x; 1.1944x over previous
//
#include <hip/hip_runtime.h>
#include <math.h>

#define NN 16384
#define BB 128
#define FF 32
#define RR 20
#define EE 262144
#define NCH 4
#define CHE (EE / NCH)

__device__ __forceinline__ float sspf(float x) {
  // softplus(x) - log(2), numerically stable
  return fmaxf(x, 0.0f) + log1pf(expf(-fabsf(x))) - 0.69314718055994531f;
}

// ---------------- K1: node embeddings hsv[n*32+f] = {hs, hvx, hvy, hvz} ----------------
__global__ __launch_bounds__(256) void k_embed(const float* __restrict__ x,
        const float* __restrict__ ws, const float* __restrict__ wv,
        float4* __restrict__ hsv) {
  int tid = blockIdx.x * 256 + threadIdx.x;   // N*8 threads
  int n = tid >> 3, fq = tid & 7;
  const float* xr = x + (size_t)n * 512;
  float acc[4][4];
#pragma unroll
  for (int k = 0; k < 4; k++)
#pragma unroll
    for (int c = 0; c < 4; c++) acc[k][c] = 0.f;
  for (int bq = 0; bq < 32; bq++) {
    float4 xs4 = *(const float4*)(xr + 4 * bq);
    float4 a0 = *(const float4*)(xr + 128 + 12 * bq);
    float4 a1 = *(const float4*)(xr + 128 + 12 * bq + 4);
    float4 a2 = *(const float4*)(xr + 128 + 12 * bq + 8);
    float xsv[4] = {xs4.x, xs4.y, xs4.z, xs4.w};
    float vv[4][3];
    vv[0][0] = a0.x; vv[0][1] = a0.y; vv[0][2] = a0.z;
    vv[1][0] = a0.w; vv[1][1] = a1.x; vv[1][2] = a1.y;
    vv[2][0] = a1.z; vv[2][1] = a1.w; vv[2][2] = a2.x;
    vv[3][0] = a2.y; vv[3][1] = a2.z; vv[3][2] = a2.w;
#pragma unroll
    for (int bb = 0; bb < 4; bb++) {
      int b = 4 * bq + bb;
      float4 w_s = *(const float4*)(ws + b * 32 + 4 * fq);
      float4 w_v = *(const float4*)(wv + b * 32 + 4 * fq);
      float wsx[4] = {w_s.x, w_s.y, w_s.z, w_s.w};
      float wvx[4] = {w_v.x, w_v.y, w_v.z, w_v.w};
#pragma unroll
      for (int k = 0; k < 4; k++) {
        acc[k][0] += xsv[bb] * wsx[k];
        acc[k][1] += vv[bb][0] * wvx[k];
        acc[k][2] += vv[bb][1] * wvx[k];
        acc[k][3] += vv[bb][2] * wvx[k];
      }
    }
  }
  const float sc = 0.088388347648318447f;  // 1/sqrt(128)
#pragma unroll
  for (int k = 0; k < 4; k++) {
    float4 o;
    o.x = acc[k][0] * sc; o.y = acc[k][1] * sc;
    o.z = acc[k][2] * sc; o.w = acc[k][3] * sc;
    hsv[(size_t)n * 32 + 4 * fq + k] = o;
  }
}

// ---------------- CSR build ----------------
__global__ __launch_bounds__(256) void k_count(const int* __restrict__ idx_i,
        int* __restrict__ cnt, int* __restrict__ pos) {
  int e = blockIdx.x * 256 + threadIdx.x;
  pos[e] = atomicAdd(cnt + idx_i[e], 1);
}

__global__ __launch_bounds__(256) void k_scan(const int* __restrict__ cnt,
        int* __restrict__ offs) {
  __shared__ int part[256];
  int t = threadIdx.x;
  int s = 0;
  for (int i = t * 64; i < t * 64 + 64; ++i) s += cnt[i];
  part[t] = s;
  __syncthreads();
  if (t == 0) {
    int run = 0;
    for (int i = 0; i < 256; i++) { int v = part[i]; part[i] = run; run += v; }
    offs[NN] = run;
  }
  __syncthreads();
  int run = part[t];
  for (int i = t * 64; i < t * 64 + 64; ++i) { offs[i] = run; run += cnt[i]; }
}

// also permutes idx_j and Yr into CSR order so k_agg streams them sequentially
__global__ __launch_bounds__(256) void k_fill(const int* __restrict__ idx_i,
        const int* __restrict__ idx_j, const float* __restrict__ Yr,
        const int* __restrict__ pos, const int* __restrict__ offs,
        int* __restrict__ elist, int* __restrict__ idxj_csr,
        float4* __restrict__ Yr_csr) {
  int e = blockIdx.x * 256 + threadIdx.x;
  int slot = offs[idx_i[e]] + pos[e];
  elist[slot] = e;
  idxj_csr[slot] = idx_j[e];
  Yr_csr[slot] = *(const float4*)(Yr + (size_t)e * 4);
}

// ---------------- fused vector output weight: Wv = w1v @ w2v * 1/sqrt(64*128) ----------------
__global__ __launch_bounds__(256) void k_wv(const float* __restrict__ w1v,
        const float* __restrict__ w2v, float* __restrict__ Wv) {
  int o = blockIdx.x * 256 + threadIdx.x;   // 8192
  int m = o >> 7, d = o & 127;
  float s = 0.f;
  for (int b = 0; b < 128; b++) s += w1v[m * 128 + b] * w2v[b * 128 + d];
  Wv[o] = s * 0.011048543456039804f;
}

// ---------------- k_wab: CSR-slot-major fused filter MLP ----------------
// Per 64-slot tile: gather fij rows, h = ssp(fij@W1+b1) in LDS, dense fp32
// GEMM h @ W2c (128 used cols) + b2, *rcut, coalesced CSR-order write.
__global__ __launch_bounds__(256) void k_wab(
        const float* __restrict__ fij, const float* __restrict__ rcut,
        const int* __restrict__ elist,
        const float* __restrict__ W1, const float* __restrict__ b1,
        const float* __restrict__ W2, const float* __restrict__ b2,
        float* __restrict__ Wab, int c0) {
  __shared__ int selist[64];
  __shared__ float sW1[640];
  __shared__ float sb1[32];
  __shared__ float sW2c[4096];     // [p][128] compact used cols (4f+k <- 6f+k)
  __shared__ float sb2c[128];
  __shared__ float sfij[20 * 66];  // [r][el], pad 66
  __shared__ float sh[64 * 36];    // [el][fp], pad 36 (16B-aligned rows)
  __shared__ float srct[64];
  int t = threadIdx.x;
  int s0 = c0 + blockIdx.x * 64;
  if (t < 64) selist[t] = elist[s0 + t];
  for (int i = t; i < 640; i += 256) sW1[i] = W1[i];
  if (t < 32) sb1[t] = b1[t];
  for (int i = t; i < 4096; i += 256) {
    int p = i >> 7, c = i & 127;
    sW2c[i] = W2[p * 192 + 6 * (c >> 2) + (c & 3)];
  }
  if (t < 128) sb2c[t] = b2[6 * (t >> 2) + (t & 3)];
  __syncthreads();
  for (int i = t; i < 1280; i += 256) {
    int row = i / 20, col = i - row * 20;
    sfij[col * 66 + row] = fij[(size_t)selist[row] * 20 + col];
  }
  if (t < 64) srct[t] = rcut[selist[t]];
  __syncthreads();
  {
    int el = t & 63, fp0 = (t >> 6) * 8;
    float acc[8];
#pragma unroll
    for (int i = 0; i < 8; i++) acc[i] = sb1[fp0 + i];
#pragma unroll
    for (int r = 0; r < 20; r++) {
      float fe = sfij[r * 66 + el];
      float4 wA = *(const float4*)(sW1 + r * 32 + fp0);
      float4 wB = *(const float4*)(sW1 + r * 32 + fp0 + 4);
      acc[0] += fe * wA.x; acc[1] += fe * wA.y;
      acc[2] += fe * wA.z; acc[3] += fe * wA.w;
      acc[4] += fe * wB.x; acc[5] += fe * wB.y;
      acc[6] += fe * wB.z; acc[7] += fe * wB.w;
    }
#pragma unroll
    for (int i = 0; i < 8; i++) sh[el * 36 + fp0 + i] = sspf(acc[i]);
  }
  __syncthreads();
  {
    int eq = t >> 4, cq = (t & 15) * 8;   // 4 edges x 8 cols per thread
    float acc[4][8];
#pragma unroll
    for (int j = 0; j < 4; j++)
#pragma unroll
      for (int i = 0; i < 8; i++) acc[j][i] = sb2c[cq + i];
#pragma unroll
    for (int p = 0; p < 32; p++) {
      float4 wA = *(const float4*)(sW2c + p * 128 + cq);
      float4 wB = *(const float4*)(sW2c + p * 128 + cq + 4);
      float w[8] = {wA.x, wA.y, wA.z, wA.w, wB.x, wB.y, wB.z, wB.w};
#pragma unroll
      for (int j = 0; j < 4; j++) {
        float hh = sh[(4 * eq + j) * 36 + p];
#pragma unroll
        for (int i = 0; i < 8; i++) acc[j][i] += hh * w[i];
      }
    }
#pragma unroll
    for (int j = 0; j < 4; j++) {
      float rc = srct[4 * eq + j];
      float* base = Wab + (size_t)(blockIdx.x * 64 + 4 * eq + j) * 128 + cq;
      float4 o1, o2;
      o1.x = acc[j][0] * rc; o1.y = acc[j][1] * rc;
      o1.z = acc[j][2] * rc; o1.w = acc[j][3] * rc;
      o2.x = acc[j][4] * rc; o2.y = acc[j][5] * rc;
      o2.z = acc[j][6] * rc; o2.w = acc[j][7] * rc;
      *(float4*)base = o1;
      *(float4*)(base + 4) = o2;
    }
  }
}

// ---------------- k_agg: one wave per node; sequential CSR streams ----------------
// lane l: f = l&31, kh = l>>5 -> cols {4f+2kh, 4f+2kh+1}. Only random access is
// hsv[j], prefetched DEPTH-2 (j fetched 3 ahead, sv issued 2 ahead).
__global__ __launch_bounds__(256) void k_agg(
        const float2* __restrict__ Wab2, const float4* __restrict__ Yr_csr,
        const int* __restrict__ idxj_csr, const float4* __restrict__ hsv,
        const int* __restrict__ offs, float* __restrict__ nagg,
        int c0, int c1) {
  int t = threadIdx.x;
  int n = blockIdx.x * 4 + (t >> 6);
  int l = t & 63, f = l & 31, kh = l >> 5;
  int start = offs[n], end = offs[n + 1];
  int s = start > c0 ? start : c0;
  int eend = end < c1 ? end : c1;
  if (s >= eend) return;    // wave-uniform exit
  float a0 = 0, a1 = 0, a2 = 0, a3 = 0, a4 = 0, a5 = 0;
  int w2i = 2 * f + kh;
  int last = eend - 1;
  // prologue: iters s (cur) and s+1 staged; j for s+2 resident
  int i1 = s + 1 < last ? s + 1 : last;
  int i2 = s + 2 < last ? s + 2 : last;
  int j0 = idxj_csr[s];
  int j1 = idxj_csr[i1];
  int j2 = idxj_csr[i2];
  float4 y0 = Yr_csr[s];
  float4 y1 = Yr_csr[i1];
  float2 d0 = Wab2[(size_t)(s - c0) * 64 + w2i];
  float2 d1 = Wab2[(size_t)(i1 - c0) * 64 + w2i];
  float4 sv0 = hsv[(size_t)j0 * 32 + f];
  float4 sv1 = hsv[(size_t)j1 * 32 + f];
  for (int ei = s; ei < eend; ++ei) {
    int in2 = ei + 2 < last ? ei + 2 : last;
    int in3 = ei + 3 < last ? ei + 3 : last;
    float4 sv2 = hsv[(size_t)j2 * 32 + f];       // issue depth-2 load
    float4 y2 = Yr_csr[in2];
    float2 d2 = Wab2[(size_t)(in2 - c0) * 64 + w2i];
    int j3 = idxj_csr[in3];
    float ys = y0.x, yx = y0.y, yy = y0.z, yz = y0.w;
    float ss = sv0.x, vx = sv0.y, vy = sv0.z, vz = sv0.w;
    if (kh == 0) {
      a0 += ss * ys * d0.x;
      a1 += (vx * yx + vy * yy + vz * yz) * 0.57735026918962576f * d0.y;
    } else {
      a0 += ss * yx * d0.x; a1 += ss * yy * d0.x; a2 += ss * yz * d0.x;
      a3 += vx * ys * d0.y; a4 += vy * ys * d0.y; a5 += vz * ys * d0.y;
    }
    y0 = y1; y1 = y2; d0 = d1; d1 = d2; sv0 = sv1; sv1 = sv2; j2 = j3;
  }
  float* na = nagg + (size_t)n * 256;
  if (kh == 0) {
    na[f] += a0;
    na[32 + f] += a1;
  } else {
    na[64 + 3 * f + 0] += a0;  na[64 + 3 * f + 1] += a1;  na[64 + 3 * f + 2] += a2;
    na[160 + 3 * f + 0] += a3; na[160 + 3 * f + 1] += a4; na[160 + 3 * f + 2] += a5;
  }
}

// ---------------- output GEMMs: W in LDS [k][d], A in register tiles ----------------
// thread = 4 nodes x 4 d; wave = 2 node-groups x 32 d-groups -> A loads are
// 2-distinct-address broadcasts, W loads are bank-perfect b128 across d.
__global__ __launch_bounds__(256) void k_os1(const float* __restrict__ na,
        const float* __restrict__ w1s, float* __restrict__ os1) {
  __shared__ float sw[8192];       // w1s [64][128]
  int t = threadIdx.x;
  for (int i = t; i < 8192; i += 256) sw[i] = w1s[i];
  __syncthreads();
  int dg = t & 31, ng = t >> 5;
  int d0 = dg * 4;
  int n0 = blockIdx.x * 32 + ng * 4;      // grid 512
  const float* ap = na + (size_t)n0 * 256;
  float acc[4][4] = {};
#pragma unroll
  for (int kq = 0; kq < 16; kq++) {
    float4 a[4];
#pragma unroll
    for (int j = 0; j < 4; j++) a[j] = *(const float4*)(ap + j * 256 + 4 * kq);
    float4 w0 = *(const float4*)(sw + (4 * kq + 0) * 128 + d0);
    float4 w1 = *(const float4*)(sw + (4 * kq + 1) * 128 + d0);
    float4 w2 = *(const float4*)(sw + (4 * kq + 2) * 128 + d0);
    float4 w3 = *(const float4*)(sw + (4 * kq + 3) * 128 + d0);
#pragma unroll
    for (int j = 0; j < 4; j++) {
      acc[j][0] += a[j].x * w0.x + a[j].y * w1.x + a[j].z * w2.x + a[j].w * w3.x;
      acc[j][1] += a[j].x * w0.y + a[j].y * w1.y + a[j].z * w2.y + a[j].w * w3.y;
      acc[j][2] += a[j].x * w0.z + a[j].y * w1.z + a[j].z * w2.z + a[j].w * w3.z;
      acc[j][3] += a[j].x * w0.w + a[j].y * w1.w + a[j].z * w2.w + a[j].w * w3.w;
    }
  }
#pragma unroll
  for (int j = 0; j < 4; j++) {
    float4 o;
    o.x = sspf(acc[j][0] * 0.125f);   // 1/sqrt(64)
    o.y = sspf(acc[j][1] * 0.125f);
    o.z = sspf(acc[j][2] * 0.125f);
    o.w = sspf(acc[j][3] * 0.125f);
    *(float4*)(os1 + (size_t)(n0 + j) * 128 + d0) = o;
  }
}

__global__ __launch_bounds__(256) void k_os2(const float* __restrict__ os1,
        const float* __restrict__ w2s, float* __restrict__ out) {
  __shared__ float sw[16384];      // w2s [128][128] = 64 KB
  int t = threadIdx.x;
  for (int i = t; i < 16384; i += 256) sw[i] = w2s[i];
  __syncthreads();
  int dg = t & 31, ng = t >> 5;
  int d0 = dg * 4;
  int n0 = blockIdx.x * 32 + ng * 4;      // grid 512
  const float* ap = os1 + (size_t)n0 * 128;
  float acc[4][4] = {};
#pragma unroll
  for (int kq = 0; kq < 32; kq++) {
    float4 a[4];
#pragma unroll
    for (int j = 0; j < 4; j++) a[j] = *(const float4*)(ap + j * 128 + 4 * kq);
    float4 w0 = *(const float4*)(sw + (4 * kq + 0) * 128 + d0);
    float4 w1 = *(const float4*)(sw + (4 * kq + 1) * 128 + d0);
    float4 w2 = *(const float4*)(sw + (4 * kq + 2) * 128 + d0);
    float4 w3 = *(const float4*)(sw + (4 * kq + 3) * 128 + d0);
#pragma unroll
    for (int j = 0; j < 4; j++) {
      acc[j][0] += a[j].x * w0.x + a[j].y * w1.x + a[j].z * w2.x + a[j].w * w3.x;
      acc[j][1] += a[j].x * w0.y + a[j].y * w1.y + a[j].z * w2.y + a[j].w * w3.y;
      acc[j][2] += a[j].x * w0.z + a[j].y * w1.z + a[j].z * w2.z + a[j].w * w3.z;
      acc[j][3] += a[j].x * w0.w + a[j].y * w1.w + a[j].z * w2.w + a[j].w * w3.w;
    }
  }
  const float sc = 0.088388347648318447f;   // 1/sqrt(128)
#pragma unroll
  for (int j = 0; j < 4; j++) {
    float4 o;
    o.x = acc[j][0] * sc; o.y = acc[j][1] * sc;
    o.z = acc[j][2] * sc; o.w = acc[j][3] * sc;
    *(float4*)(out + (size_t)(n0 + j) * 512 + d0) = o;
  }
}

// thread = 2 nodes x 4 d x 3 comps
__global__ __launch_bounds__(256) void k_ov(const float* __restrict__ na,
        const float* __restrict__ Wv, float* __restrict__ out) {
  __shared__ float sw[8192];       // Wv [64][128]
  int t = threadIdx.x;
  for (int i = t; i < 8192; i += 256) sw[i] = Wv[i];
  __syncthreads();
  int dg = t & 31, ng = t >> 5;
  int d0 = dg * 4;
  int n0 = blockIdx.x * 16 + ng * 2;      // grid 1024
  const float* ap = na + (size_t)n0 * 256 + 64;   // v_in row: 192 contiguous
  float acc[2][12] = {};
#pragma unroll
  for (int mq = 0; mq < 16; mq++) {
    float4 p[2][3];
#pragma unroll
    for (int j = 0; j < 2; j++) {
      p[j][0] = *(const float4*)(ap + j * 256 + 12 * mq);
      p[j][1] = *(const float4*)(ap + j * 256 + 12 * mq + 4);
      p[j][2] = *(const float4*)(ap + j * 256 + 12 * mq + 8);
    }
    float4 w0 = *(const float4*)(sw + (4 * mq + 0) * 128 + d0);
    float4 w1 = *(const float4*)(sw + (4 * mq + 1) * 128 + d0);
    float4 w2 = *(const float4*)(sw + (4 * mq + 2) * 128 + d0);
    float4 w3 = *(const float4*)(sw + (4 * mq + 3) * 128 + d0);
#pragma unroll
    for (int j = 0; j < 2; j++) {
      float vm[4][3];
      vm[0][0] = p[j][0].x; vm[0][1] = p[j][0].y; vm[0][2] = p[j][0].z;
      vm[1][0] = p[j][0].w; vm[1][1] = p[j][1].x; vm[1][2] = p[j][1].y;
      vm[2][0] = p[j][1].z; vm[2][1] = p[j][1].w; vm[2][2] = p[j][2].x;
      vm[3][0] = p[j][2].y; vm[3][1] = p[j][2].z; vm[3][2] = p[j][2].w;
      float wm[4][4];
      wm[0][0] = w0.x; wm[0][1] = w0.y; wm[0][2] = w0.z; wm[0][3] = w0.w;
      wm[1][0] = w1.x; wm[1][1] = w1.y; wm[1][2] = w1.z; wm[1][3] = w1.w;
      wm[2][0] = w2.x; wm[2][1] = w2.y; wm[2][2] = w2.z; wm[2][3] = w2.w;
      wm[3][0] = w3.x; wm[3][1] = w3.y; wm[3][2] = w3.z; wm[3][3] = w3.w;
#pragma unroll
      for (int m = 0; m < 4; m++)
#pragma unroll
        for (int i = 0; i < 4; i++)
#pragma unroll
          for (int c = 0; c < 3; c++)
            acc[j][i * 3 + c] += vm[m][c] * wm[m][i];
    }
  }
#pragma unroll
  for (int j = 0; j < 2; j++) {
    float* op = out + (size_t)(n0 + j) * 512 + 128 + 12 * dg;
    float4 o0, o1, o2;
    o0.x = acc[j][0]; o0.y = acc[j][1]; o0.z = acc[j][2]; o0.w = acc[j][3];
    o1.x = acc[j][4]; o1.y = acc[j][5]; o1.z = acc[j][6]; o1.w = acc[j][7];
    o2.x = acc[j][8]; o2.y = acc[j][9]; o2.z = acc[j][10]; o2.w = acc[j][11];
    *(float4*)op = o0;
    *(float4*)(op + 4) = o1;
    *(float4*)(op + 8) = o2;
  }
}

extern "C" void kernel_launch(void* const* d_in, const int* in_sizes, int n_in,
                              void* d_out, int out_size, void* d_ws, size_t ws_size,
                              hipStream_t stream) {
  const float* x    = (const float*)d_in[0];
  const int*   idx_i = (const int*)d_in[1];
  const int*   idx_j = (const int*)d_in[2];
  const float* fij  = (const float*)d_in[3];
  const float* rcut = (const float*)d_in[4];
  const float* Yr   = (const float*)d_in[5];
  const float* w_s  = (const float*)d_in[6];
  const float* w_v  = (const float*)d_in[7];
  const float* W1   = (const float*)d_in[8];
  const float* b1   = (const float*)d_in[9];
  const float* W2   = (const float*)d_in[10];
  const float* b2   = (const float*)d_in[11];
  const float* w1s  = (const float*)d_in[12];
  const float* w1v  = (const float*)d_in[13];
  const float* w2s  = (const float*)d_in[14];
  const float* w2v  = (const float*)d_in[15];
  float* out = (float*)d_out;

  char* ws = (char*)d_ws;
  size_t off = 0;
  auto alloc = [&](size_t bytes) {
    void* p = ws + off;
    off += (bytes + 255) & ~(size_t)255;
    return p;
  };
  float4* hsv   = (float4*)alloc((size_t)NN * 32 * 16);
  float*  nagg  = (float*)alloc((size_t)NN * 256 * 4);
  float*  Wab   = (float*)alloc((size_t)CHE * 128 * 4);   // per-chunk; reused
  float*  os1   = Wab;    // alias: Wab dead before k_os1 runs
  float4* Yr_csr = (float4*)alloc((size_t)EE * 16);
  int* idxj_csr = (int*)alloc((size_t)EE * 4);
  float* Wv     = (float*)alloc((size_t)8192 * 4);
  int* cnt      = (int*)alloc((size_t)NN * 4);
  int* offs     = (int*)alloc((size_t)(NN + 1) * 4);
  int* pos      = (int*)alloc((size_t)EE * 4);
  int* elist    = (int*)alloc((size_t)EE * 4);

  hipMemsetAsync(cnt, 0, (size_t)NN * 4, stream);
  hipMemsetAsync(nagg, 0, (size_t)NN * 256 * 4, stream);
  k_count<<<EE / 256, 256, 0, stream>>>(idx_i, cnt, pos);
  k_scan<<<1, 256, 0, stream>>>(cnt, offs);
  k_fill<<<EE / 256, 256, 0, stream>>>(idx_i, idx_j, Yr, pos, offs,
                                       elist, idxj_csr, Yr_csr);
  k_embed<<<NN * 8 / 256, 256, 0, stream>>>(x, w_s, w_v, hsv);
  k_wv<<<32, 256, 0, stream>>>(w1v, w2v, Wv);
  for (int ch = 0; ch < NCH; ch++) {
    int c0 = ch * CHE, c1 = c0 + CHE;
    k_wab<<<CHE / 64, 256, 0, stream>>>(fij, rcut, elist, W1, b1, W2, b2,
                                        Wab, c0);
    k_agg<<<NN / 4, 256, 0, stream>>>((const float2*)Wab, Yr_csr, idxj_csr,
                                      hsv, offs, nagg, c0, c1);
  }
  k_os1<<<512, 256, 0, stream>>>(nagg, w1s, os1);
  k_os2<<<512, 256, 0, stream>>>(os1, w2s, out);
  k_ov<<<1024, 256, 0, stream>>>(nagg, Wv, out);
}

// Round 8
// 287.297 us; speedup vs baseline: 1.2850x; 1.0759x over previous
//
#include <hip/hip_runtime.h>
#include <math.h>

#define NN 16384
#define BB 128
#define FF 32
#define RR 20
#define EE 262144
#define NCH 2
#define CHE (EE / NCH)

__device__ __forceinline__ float sspf(float x) {
  // softplus(x) - log(2), numerically stable
  return fmaxf(x, 0.0f) + log1pf(expf(-fabsf(x))) - 0.69314718055994531f;
}

// ---------------- K1: node embeddings, x rows staged in LDS ----------------
// block = 32 nodes; stage 32x512 floats (row pad +4 -> conflict-free b128).
__global__ __launch_bounds__(256) void k_embed(const float* __restrict__ x,
        const float* __restrict__ ws, const float* __restrict__ wv,
        float4* __restrict__ hsv) {
  __shared__ float sx[32 * 516];   // 66 KB
  int t = threadIdx.x;
  int b0 = blockIdx.x * 32;        // 512 blocks
  const float4* xg = (const float4*)(x + (size_t)b0 * 512);
  for (int i = t; i < 4096; i += 256) {
    int row = i >> 7, col = i & 127;
    *(float4*)(sx + row * 516 + col * 4) = xg[i];
  }
  __syncthreads();
  int n = t >> 3, fq = t & 7;
  const float* xr = sx + n * 516;
  float acc[4][4];
#pragma unroll
  for (int k = 0; k < 4; k++)
#pragma unroll
    for (int c = 0; c < 4; c++) acc[k][c] = 0.f;
  for (int bq = 0; bq < 32; bq++) {
    float4 xs4 = *(const float4*)(xr + 4 * bq);
    float4 a0 = *(const float4*)(xr + 128 + 12 * bq);
    float4 a1 = *(const float4*)(xr + 128 + 12 * bq + 4);
    float4 a2 = *(const float4*)(xr + 128 + 12 * bq + 8);
    float xsv[4] = {xs4.x, xs4.y, xs4.z, xs4.w};
    float vv[4][3];
    vv[0][0] = a0.x; vv[0][1] = a0.y; vv[0][2] = a0.z;
    vv[1][0] = a0.w; vv[1][1] = a1.x; vv[1][2] = a1.y;
    vv[2][0] = a1.z; vv[2][1] = a1.w; vv[2][2] = a2.x;
    vv[3][0] = a2.y; vv[3][1] = a2.z; vv[3][2] = a2.w;
#pragma unroll
    for (int bb = 0; bb < 4; bb++) {
      int b = 4 * bq + bb;
      float4 w_s = *(const float4*)(ws + b * 32 + 4 * fq);
      float4 w_v = *(const float4*)(wv + b * 32 + 4 * fq);
      float wsx[4] = {w_s.x, w_s.y, w_s.z, w_s.w};
      float wvx[4] = {w_v.x, w_v.y, w_v.z, w_v.w};
#pragma unroll
      for (int k = 0; k < 4; k++) {
        acc[k][0] += xsv[bb] * wsx[k];
        acc[k][1] += vv[bb][0] * wvx[k];
        acc[k][2] += vv[bb][1] * wvx[k];
        acc[k][3] += vv[bb][2] * wvx[k];
      }
    }
  }
  const float sc = 0.088388347648318447f;  // 1/sqrt(128)
#pragma unroll
  for (int k = 0; k < 4; k++) {
    float4 o;
    o.x = acc[k][0] * sc; o.y = acc[k][1] * sc;
    o.z = acc[k][2] * sc; o.w = acc[k][3] * sc;
    hsv[(size_t)(b0 + n) * 32 + 4 * fq + k] = o;
  }
}

// ---------------- CSR build ----------------
__global__ __launch_bounds__(256) void k_count(const int* __restrict__ idx_i,
        int* __restrict__ cnt, int* __restrict__ pos) {
  int e = blockIdx.x * 256 + threadIdx.x;
  pos[e] = atomicAdd(cnt + idx_i[e], 1);
}

__global__ __launch_bounds__(256) void k_scan(const int* __restrict__ cnt,
        int* __restrict__ offs) {
  __shared__ int part[256];
  int t = threadIdx.x;
  int s = 0;
  for (int i = t * 64; i < t * 64 + 64; ++i) s += cnt[i];
  part[t] = s;
  __syncthreads();
  if (t == 0) {
    int run = 0;
    for (int i = 0; i < 256; i++) { int v = part[i]; part[i] = run; run += v; }
    offs[NN] = run;
  }
  __syncthreads();
  int run = part[t];
  for (int i = t * 64; i < t * 64 + 64; ++i) { offs[i] = run; run += cnt[i]; }
}

// also permutes idx_j and Yr into CSR order so k_agg streams them sequentially
__global__ __launch_bounds__(256) void k_fill(const int* __restrict__ idx_i,
        const int* __restrict__ idx_j, const float* __restrict__ Yr,
        const int* __restrict__ pos, const int* __restrict__ offs,
        int* __restrict__ elist, int* __restrict__ idxj_csr,
        float4* __restrict__ Yr_csr) {
  int e = blockIdx.x * 256 + threadIdx.x;
  int slot = offs[idx_i[e]] + pos[e];
  elist[slot] = e;
  idxj_csr[slot] = idx_j[e];
  Yr_csr[slot] = *(const float4*)(Yr + (size_t)e * 4);
}

// ---------------- fused vector output weight: Wv = w1v @ w2v * 1/sqrt(64*128) ----------------
__global__ __launch_bounds__(256) void k_wv(const float* __restrict__ w1v,
        const float* __restrict__ w2v, float* __restrict__ Wv) {
  int o = blockIdx.x * 256 + threadIdx.x;   // 8192
  int m = o >> 7, d = o & 127;
  float s = 0.f;
  for (int b = 0; b < 128; b++) s += w1v[m * 128 + b] * w2v[b * 128 + d];
  Wv[o] = s * 0.011048543456039804f;
}

// ---------------- k_wab: CSR-slot-major fused filter MLP, 128-slot tiles ----------------
__global__ __launch_bounds__(256) void k_wab(
        const float* __restrict__ fij, const float* __restrict__ rcut,
        const int* __restrict__ elist,
        const float* __restrict__ W1, const float* __restrict__ b1,
        const float* __restrict__ W2, const float* __restrict__ b2,
        float* __restrict__ Wab, int c0) {
  __shared__ int selist[128];
  __shared__ float sW1[640];
  __shared__ float sb1[32];
  __shared__ float sW2c[4096];     // [p][128] compact used cols (4f+k <- 6f+k)
  __shared__ float sb2c[128];
  __shared__ float sfij[20 * 130]; // [r][el], pad 130
  __shared__ float sh[128 * 37];   // [el][fp], pad 37 (eq-group bank spread)
  __shared__ float srct[128];
  int t = threadIdx.x;
  int s0 = c0 + blockIdx.x * 128;
  if (t < 128) selist[t] = elist[s0 + t];
  for (int i = t; i < 640; i += 256) sW1[i] = W1[i];
  if (t < 32) sb1[t] = b1[t];
  for (int i = t; i < 4096; i += 256) {
    int p = i >> 7, c = i & 127;
    sW2c[i] = W2[p * 192 + 6 * (c >> 2) + (c & 3)];
  }
  if (t < 128) sb2c[t] = b2[6 * (t >> 2) + (t & 3)];
  __syncthreads();
  for (int i = t; i < 2560; i += 256) {
    int row = i / 20, col = i - row * 20;
    sfij[col * 130 + row] = fij[(size_t)selist[row] * 20 + col];
  }
  if (t < 128) srct[t] = rcut[selist[t]];
  __syncthreads();
  {
    int el = t & 127, fp0 = (t >> 7) * 16;
    float acc[16];
#pragma unroll
    for (int i = 0; i < 16; i++) acc[i] = sb1[fp0 + i];
#pragma unroll
    for (int r = 0; r < 20; r++) {
      float fe = sfij[r * 130 + el];
      float4 wA = *(const float4*)(sW1 + r * 32 + fp0);
      float4 wB = *(const float4*)(sW1 + r * 32 + fp0 + 4);
      float4 wC = *(const float4*)(sW1 + r * 32 + fp0 + 8);
      float4 wD = *(const float4*)(sW1 + r * 32 + fp0 + 12);
      acc[0] += fe * wA.x;  acc[1] += fe * wA.y;
      acc[2] += fe * wA.z;  acc[3] += fe * wA.w;
      acc[4] += fe * wB.x;  acc[5] += fe * wB.y;
      acc[6] += fe * wB.z;  acc[7] += fe * wB.w;
      acc[8] += fe * wC.x;  acc[9] += fe * wC.y;
      acc[10] += fe * wC.z; acc[11] += fe * wC.w;
      acc[12] += fe * wD.x; acc[13] += fe * wD.y;
      acc[14] += fe * wD.z; acc[15] += fe * wD.w;
    }
#pragma unroll
    for (int i = 0; i < 16; i++) sh[el * 37 + fp0 + i] = sspf(acc[i]);
  }
  __syncthreads();
  {
    int eq = t >> 4, cq = (t & 15) * 8;   // 8 edges x 8 cols per thread
    float acc[8][8];
#pragma unroll
    for (int j = 0; j < 8; j++)
#pragma unroll
      for (int i = 0; i < 8; i++) acc[j][i] = sb2c[cq + i];
#pragma unroll
    for (int p = 0; p < 32; p++) {
      float4 wA = *(const float4*)(sW2c + p * 128 + cq);
      float4 wB = *(const float4*)(sW2c + p * 128 + cq + 4);
      float w[8] = {wA.x, wA.y, wA.z, wA.w, wB.x, wB.y, wB.z, wB.w};
#pragma unroll
      for (int j = 0; j < 8; j++) {
        float hh = sh[(8 * eq + j) * 37 + p];
#pragma unroll
        for (int i = 0; i < 8; i++) acc[j][i] += hh * w[i];
      }
    }
#pragma unroll
    for (int j = 0; j < 8; j++) {
      float rc = srct[8 * eq + j];
      float* base = Wab + (size_t)(blockIdx.x * 128 + 8 * eq + j) * 128 + cq;
      float4 o1, o2;
      o1.x = acc[j][0] * rc; o1.y = acc[j][1] * rc;
      o1.z = acc[j][2] * rc; o1.w = acc[j][3] * rc;
      o2.x = acc[j][4] * rc; o2.y = acc[j][5] * rc;
      o2.z = acc[j][6] * rc; o2.w = acc[j][7] * rc;
      *(float4*)base = o1;
      *(float4*)(base + 4) = o2;
    }
  }
}

// ---------------- k_agg: one wave per node; sequential CSR streams ----------------
// lane l: f = l&31, kh = l>>5 -> cols {4f+2kh, 4f+2kh+1}. Only random access is
// hsv[j], prefetched DEPTH-2 (j fetched 3 ahead, sv issued 2 ahead).
__global__ __launch_bounds__(256) void k_agg(
        const float2* __restrict__ Wab2, const float4* __restrict__ Yr_csr,
        const int* __restrict__ idxj_csr, const float4* __restrict__ hsv,
        const int* __restrict__ offs, float* __restrict__ nagg,
        int c0, int c1) {
  int t = threadIdx.x;
  int n = blockIdx.x * 4 + (t >> 6);
  int l = t & 63, f = l & 31, kh = l >> 5;
  int start = offs[n], end = offs[n + 1];
  int s = start > c0 ? start : c0;
  int eend = end < c1 ? end : c1;
  if (s >= eend) return;    // wave-uniform exit
  float a0 = 0, a1 = 0, a2 = 0, a3 = 0, a4 = 0, a5 = 0;
  int w2i = 2 * f + kh;
  int last = eend - 1;
  // prologue: iters s (cur) and s+1 staged; j for s+2 resident
  int i1 = s + 1 < last ? s + 1 : last;
  int i2 = s + 2 < last ? s + 2 : last;
  int j0 = idxj_csr[s];
  int j1 = idxj_csr[i1];
  int j2 = idxj_csr[i2];
  float4 y0 = Yr_csr[s];
  float4 y1 = Yr_csr[i1];
  float2 d0 = Wab2[(size_t)(s - c0) * 64 + w2i];
  float2 d1 = Wab2[(size_t)(i1 - c0) * 64 + w2i];
  float4 sv0 = hsv[(size_t)j0 * 32 + f];
  float4 sv1 = hsv[(size_t)j1 * 32 + f];
  for (int ei = s; ei < eend; ++ei) {
    int in2 = ei + 2 < last ? ei + 2 : last;
    int in3 = ei + 3 < last ? ei + 3 : last;
    float4 sv2 = hsv[(size_t)j2 * 32 + f];       // issue depth-2 load
    float4 y2 = Yr_csr[in2];
    float2 d2 = Wab2[(size_t)(in2 - c0) * 64 + w2i];
    int j3 = idxj_csr[in3];
    float ys = y0.x, yx = y0.y, yy = y0.z, yz = y0.w;
    float ss = sv0.x, vx = sv0.y, vy = sv0.z, vz = sv0.w;
    if (kh == 0) {
      a0 += ss * ys * d0.x;
      a1 += (vx * yx + vy * yy + vz * yz) * 0.57735026918962576f * d0.y;
    } else {
      a0 += ss * yx * d0.x; a1 += ss * yy * d0.x; a2 += ss * yz * d0.x;
      a3 += vx * ys * d0.y; a4 += vy * ys * d0.y; a5 += vz * ys * d0.y;
    }
    y0 = y1; y1 = y2; d0 = d1; d1 = d2; sv0 = sv1; sv1 = sv2; j2 = j3;
  }
  float* na = nagg + (size_t)n * 256;
  if (kh == 0) {
    na[f] += a0;
    na[32 + f] += a1;
  } else {
    na[64 + 3 * f + 0] += a0;  na[64 + 3 * f + 1] += a1;  na[64 + 3 * f + 2] += a2;
    na[160 + 3 * f + 0] += a3; na[160 + 3 * f + 1] += a4; na[160 + 3 * f + 2] += a5;
  }
}

// ---------------- output GEMMs: W in LDS [k][d], A in register tiles ----------------
__global__ __launch_bounds__(256) void k_os1(const float* __restrict__ na,
        const float* __restrict__ w1s, float* __restrict__ os1) {
  __shared__ float sw[8192];       // w1s [64][128]
  int t = threadIdx.x;
  for (int i = t; i < 8192; i += 256) sw[i] = w1s[i];
  __syncthreads();
  int dg = t & 31, ng = t >> 5;
  int d0 = dg * 4;
  int n0 = blockIdx.x * 32 + ng * 4;      // grid 512
  const float* ap = na + (size_t)n0 * 256;
  float acc[4][4] = {};
#pragma unroll
  for (int kq = 0; kq < 16; kq++) {
    float4 a[4];
#pragma unroll
    for (int j = 0; j < 4; j++) a[j] = *(const float4*)(ap + j * 256 + 4 * kq);
    float4 w0 = *(const float4*)(sw + (4 * kq + 0) * 128 + d0);
    float4 w1 = *(const float4*)(sw + (4 * kq + 1) * 128 + d0);
    float4 w2 = *(const float4*)(sw + (4 * kq + 2) * 128 + d0);
    float4 w3 = *(const float4*)(sw + (4 * kq + 3) * 128 + d0);
#pragma unroll
    for (int j = 0; j < 4; j++) {
      acc[j][0] += a[j].x * w0.x + a[j].y * w1.x + a[j].z * w2.x + a[j].w * w3.x;
      acc[j][1] += a[j].x * w0.y + a[j].y * w1.y + a[j].z * w2.y + a[j].w * w3.y;
      acc[j][2] += a[j].x * w0.z + a[j].y * w1.z + a[j].z * w2.z + a[j].w * w3.z;
      acc[j][3] += a[j].x * w0.w + a[j].y * w1.w + a[j].z * w2.w + a[j].w * w3.w;
    }
  }
#pragma unroll
  for (int j = 0; j < 4; j++) {
    float4 o;
    o.x = sspf(acc[j][0] * 0.125f);   // 1/sqrt(64)
    o.y = sspf(acc[j][1] * 0.125f);
    o.z = sspf(acc[j][2] * 0.125f);
    o.w = sspf(acc[j][3] * 0.125f);
    *(float4*)(os1 + (size_t)(n0 + j) * 128 + d0) = o;
  }
}

__global__ __launch_bounds__(256) void k_os2(const float* __restrict__ os1,
        const float* __restrict__ w2s, float* __restrict__ out) {
  __shared__ float sw[16384];      // w2s [128][128] = 64 KB
  int t = threadIdx.x;
  for (int i = t; i < 16384; i += 256) sw[i] = w2s[i];
  __syncthreads();
  int dg = t & 31, ng = t >> 5;
  int d0 = dg * 4;
  int n0 = blockIdx.x * 32 + ng * 4;      // grid 512
  const float* ap = os1 + (size_t)n0 * 128;
  float acc[4][4] = {};
#pragma unroll
  for (int kq = 0; kq < 32; kq++) {
    float4 a[4];
#pragma unroll
    for (int j = 0; j < 4; j++) a[j] = *(const float4*)(ap + j * 128 + 4 * kq);
    float4 w0 = *(const float4*)(sw + (4 * kq + 0) * 128 + d0);
    float4 w1 = *(const float4*)(sw + (4 * kq + 1) * 128 + d0);
    float4 w2 = *(const float4*)(sw + (4 * kq + 2) * 128 + d0);
    float4 w3 = *(const float4*)(sw + (4 * kq + 3) * 128 + d0);
#pragma unroll
    for (int j = 0; j < 4; j++) {
      acc[j][0] += a[j].x * w0.x + a[j].y * w1.x + a[j].z * w2.x + a[j].w * w3.x;
      acc[j][1] += a[j].x * w0.y + a[j].y * w1.y + a[j].z * w2.y + a[j].w * w3.y;
      acc[j][2] += a[j].x * w0.z + a[j].y * w1.z + a[j].z * w2.z + a[j].w * w3.z;
      acc[j][3] += a[j].x * w0.w + a[j].y * w1.w + a[j].z * w2.w + a[j].w * w3.w;
    }
  }
  const float sc = 0.088388347648318447f;   // 1/sqrt(128)
#pragma unroll
  for (int j = 0; j < 4; j++) {
    float4 o;
    o.x = acc[j][0] * sc; o.y = acc[j][1] * sc;
    o.z = acc[j][2] * sc; o.w = acc[j][3] * sc;
    *(float4*)(out + (size_t)(n0 + j) * 512 + d0) = o;
  }
}

// thread = 2 nodes x 4 d x 3 comps
__global__ __launch_bounds__(256) void k_ov(const float* __restrict__ na,
        const float* __restrict__ Wv, float* __restrict__ out) {
  __shared__ float sw[8192];       // Wv [64][128]
  int t = threadIdx.x;
  for (int i = t; i < 8192; i += 256) sw[i] = Wv[i];
  __syncthreads();
  int dg = t & 31, ng = t >> 5;
  int d0 = dg * 4;
  int n0 = blockIdx.x * 16 + ng * 2;      // grid 1024
  const float* ap = na + (size_t)n0 * 256 + 64;   // v_in row: 192 contiguous
  float acc[2][12] = {};
#pragma unroll
  for (int mq = 0; mq < 16; mq++) {
    float4 p[2][3];
#pragma unroll
    for (int j = 0; j < 2; j++) {
      p[j][0] = *(const float4*)(ap + j * 256 + 12 * mq);
      p[j][1] = *(const float4*)(ap + j * 256 + 12 * mq + 4);
      p[j][2] = *(const float4*)(ap + j * 256 + 12 * mq + 8);
    }
    float4 w0 = *(const float4*)(sw + (4 * mq + 0) * 128 + d0);
    float4 w1 = *(const float4*)(sw + (4 * mq + 1) * 128 + d0);
    float4 w2 = *(const float4*)(sw + (4 * mq + 2) * 128 + d0);
    float4 w3 = *(const float4*)(sw + (4 * mq + 3) * 128 + d0);
#pragma unroll
    for (int j = 0; j < 2; j++) {
      float vm[4][3];
      vm[0][0] = p[j][0].x; vm[0][1] = p[j][0].y; vm[0][2] = p[j][0].z;
      vm[1][0] = p[j][0].w; vm[1][1] = p[j][1].x; vm[1][2] = p[j][1].y;
      vm[2][0] = p[j][1].z; vm[2][1] = p[j][1].w; vm[2][2] = p[j][2].x;
      vm[3][0] = p[j][2].y; vm[3][1] = p[j][2].z; vm[3][2] = p[j][2].w;
      float wm[4][4];
      wm[0][0] = w0.x; wm[0][1] = w0.y; wm[0][2] = w0.z; wm[0][3] = w0.w;
      wm[1][0] = w1.x; wm[1][1] = w1.y; wm[1][2] = w1.z; wm[1][3] = w1.w;
      wm[2][0] = w2.x; wm[2][1] = w2.y; wm[2][2] = w2.z; wm[2][3] = w2.w;
      wm[3][0] = w3.x; wm[3][1] = w3.y; wm[3][2] = w3.z; wm[3][3] = w3.w;
#pragma unroll
      for (int m = 0; m < 4; m++)
#pragma unroll
        for (int i = 0; i < 4; i++)
#pragma unroll
          for (int c = 0; c < 3; c++)
            acc[j][i * 3 + c] += vm[m][c] * wm[m][i];
    }
  }
#pragma unroll
  for (int j = 0; j < 2; j++) {
    float* op = out + (size_t)(n0 + j) * 512 + 128 + 12 * dg;
    float4 o0, o1, o2;
    o0.x = acc[j][0]; o0.y = acc[j][1]; o0.z = acc[j][2]; o0.w = acc[j][3];
    o1.x = acc[j][4]; o1.y = acc[j][5]; o1.z = acc[j][6]; o1.w = acc[j][7];
    o2.x = acc[j][8]; o2.y = acc[j][9]; o2.z = acc[j][10]; o2.w = acc[j][11];
    *(float4*)op = o0;
    *(float4*)(op + 4) = o1;
    *(float4*)(op + 8) = o2;
  }
}

extern "C" void kernel_launch(void* const* d_in, const int* in_sizes, int n_in,
                              void* d_out, int out_size, void* d_ws, size_t ws_size,
                              hipStream_t stream) {
  const float* x    = (const float*)d_in[0];
  const int*   idx_i = (const int*)d_in[1];
  const int*   idx_j = (const int*)d_in[2];
  const float* fij  = (const float*)d_in[3];
  const float* rcut = (const float*)d_in[4];
  const float* Yr   = (const float*)d_in[5];
  const float* w_s  = (const float*)d_in[6];
  const float* w_v  = (const float*)d_in[7];
  const float* W1   = (const float*)d_in[8];
  const float* b1   = (const float*)d_in[9];
  const float* W2   = (const float*)d_in[10];
  const float* b2   = (const float*)d_in[11];
  const float* w1s  = (const float*)d_in[12];
  const float* w1v  = (const float*)d_in[13];
  const float* w2s  = (const float*)d_in[14];
  const float* w2v  = (const float*)d_in[15];
  float* out = (float*)d_out;

  char* ws = (char*)d_ws;
  size_t off = 0;
  auto alloc = [&](size_t bytes) {
    void* p = ws + off;
    off += (bytes + 255) & ~(size_t)255;
    return p;
  };
  float4* hsv   = (float4*)alloc((size_t)NN * 32 * 16);
  float*  nagg  = (float*)alloc((size_t)NN * 256 * 4);
  float*  Wab   = (float*)alloc((size_t)CHE * 128 * 4);   // per-chunk; reused (67 MB)
  float*  os1   = Wab;    // alias: Wab dead before k_os1 runs
  float4* Yr_csr = (float4*)alloc((size_t)EE * 16);
  int* idxj_csr = (int*)alloc((size_t)EE * 4);
  float* Wv     = (float*)alloc((size_t)8192 * 4);
  int* cnt      = (int*)alloc((size_t)NN * 4);
  int* offs     = (int*)alloc((size_t)(NN + 1) * 4);
  int* pos      = (int*)alloc((size_t)EE * 4);
  int* elist    = (int*)alloc((size_t)EE * 4);

  hipMemsetAsync(cnt, 0, (size_t)NN * 4, stream);
  hipMemsetAsync(nagg, 0, (size_t)NN * 256 * 4, stream);
  k_count<<<EE / 256, 256, 0, stream>>>(idx_i, cnt, pos);
  k_scan<<<1, 256, 0, stream>>>(cnt, offs);
  k_fill<<<EE / 256, 256, 0, stream>>>(idx_i, idx_j, Yr, pos, offs,
                                       elist, idxj_csr, Yr_csr);
  k_embed<<<NN / 32, 256, 0, stream>>>(x, w_s, w_v, hsv);
  k_wv<<<32, 256, 0, stream>>>(w1v, w2v, Wv);
  for (int ch = 0; ch < NCH; ch++) {
    int c0 = ch * CHE, c1 = c0 + CHE;
    k_wab<<<CHE / 128, 256, 0, stream>>>(fij, rcut, elist, W1, b1, W2, b2,
                                         Wab, c0);
    k_agg<<<NN / 4, 256, 0, stream>>>((const float2*)Wab, Yr_csr, idxj_csr,
                                      hsv, offs, nagg, c0, c1);
  }
  k_os1<<<512, 256, 0, stream>>>(nagg, w1s, os1);
  k_os2<<<512, 256, 0, stream>>>(os1, w2s, out);
  k_ov<<<1024, 256, 0, stream>>>(nagg, Wv, out);
}